// Round 1
// baseline (1036.399 us; speedup 1.0000x reference)
//
#include <hip/hip_runtime.h>
#include <math.h>

#define BB 8
#define CIN 256
#define COUT 256
#define HH 64
#define WW 64
#define OCM 27          // 18 offset + 9 mod channels
#define KTOT (CIN * 9)  // 2304
#define KC 36           // K-chunk: 4 channels x 9 taps

// ---------------- ws layout (floats) ----------------
// wT     [KTOT][COUT]      at 0          (589824 floats)
// womT   [KTOT][32]        at 589824     (73728 floats)
// offmod [BB][OCM][HH][WW] at 663552     (884736 floats)
#define WS_WT 0
#define WS_WOMT 589824
#define WS_OFFMOD 663552

// K0a: transpose reg_w [COUT][KTOT] -> wT [KTOT][COUT]
__global__ void k_transpose_w(const float* __restrict__ rw, float* __restrict__ wT) {
    int t = blockIdx.x * blockDim.x + threadIdx.x;
    if (t >= COUT * KTOT) return;
    int n = t / KTOT;
    int k = t % KTOT;
    wT[k * COUT + n] = rw[t];
}

// K0b: pack offset_w[18][KTOT] + mod_w[9][KTOT] -> womT [KTOT][32]
__global__ void k_pack_wom(const float* __restrict__ ow, const float* __restrict__ mw,
                           float* __restrict__ womT) {
    int t = blockIdx.x * blockDim.x + threadIdx.x;
    if (t >= KTOT * 32) return;
    int k = t >> 5;
    int oc = t & 31;
    float v = 0.f;
    if (oc < 18) v = ow[oc * KTOT + k];
    else if (oc < 27) v = mw[(oc - 18) * KTOT + k];
    womT[t] = v;
}

// K1: offset/mod conv. block = (b,h) row, 256 thr = 64 w x 4 channel-groups.
__global__ __launch_bounds__(256) void k_offmod(
    const float* __restrict__ x, const float* __restrict__ womT,
    const float* __restrict__ ob, const float* __restrict__ mb,
    float* __restrict__ offmod)
{
    const int h = blockIdx.x, b = blockIdx.y;
    const int t = threadIdx.x;
    const int w = t & 63;
    const int cg = __builtin_amdgcn_readfirstlane(t >> 6);  // wave-uniform -> s_loads for weights

    float acc[OCM];
#pragma unroll
    for (int i = 0; i < OCM; ++i) acc[i] = 0.f;

    const float* xb = x + (size_t)b * CIN * HH * WW;
    for (int ci = 0; ci < 64; ++ci) {
        int c = cg * 64 + ci;
        const float* xc = xb + (size_t)c * HH * WW;
#pragma unroll
        for (int ky = 0; ky < 3; ++ky) {
            int y = h + ky - 1;
            bool yok = (unsigned)y < HH;
            const float* xr = xc + y * WW;
            const float* wp = womT + (size_t)(c * 9 + ky * 3) * 32;
#pragma unroll
            for (int kx = 0; kx < 3; ++kx) {
                int xx = w + kx - 1;
                float xv = (yok && (unsigned)xx < WW) ? xr[xx] : 0.f;
#pragma unroll
                for (int oc = 0; oc < OCM; ++oc)
                    acc[oc] += xv * wp[kx * 32 + oc];
            }
        }
    }

    __shared__ float red[4][OCM][64];
#pragma unroll
    for (int i = 0; i < OCM; ++i) red[cg][i][w] = acc[i];
    __syncthreads();

    for (int r = t; r < OCM * 64; r += 256) {
        int oc = r >> 6;
        int ww = r & 63;
        float s = red[0][oc][ww] + red[1][oc][ww] + red[2][oc][ww] + red[3][oc][ww];
        float outv;
        if (oc < 18) {
            s += ob[oc];
            outv = fminf(fmaxf(s, -16.f), 16.f);  // max_offset = 64/4
        } else {
            outv = 1.f / (1.f + __expf(-(s + mb[oc - 18])));
        }
        offmod[(((size_t)b * OCM + oc) * HH + h) * WW + ww] = outv;
    }
}

// K2: deformable conv as fused gather + GEMM.
// block = (b,h): M-tile = 64 (w row), N = 256, K = 2304 in chunks of 36.
__global__ __launch_bounds__(256) void k_deform(
    const float* __restrict__ x, const float* __restrict__ offmod,
    const float* __restrict__ wT, float* __restrict__ out)
{
    const int h = blockIdx.x, b = blockIdx.y;
    const int t = threadIdx.x;
    const int j = t & 15;   // n-lane: owns n = j + 16*q
    const int i4 = (t >> 4) * 4;  // m-base: owns m = i4..i4+3

    __shared__ int   SIDX[9][4][64];
    __shared__ float SW[9][4][64];
    __shared__ float VAL[KC][64];
    __shared__ float WTs[KC][COUT];

    // ---- build sample tables: 576 (m,tap) pairs ----
    const float* om = offmod + (size_t)b * OCM * HH * WW;
    for (int p = t; p < 64 * 9; p += 256) {
        int m = p & 63, tap = p >> 6;
        float dy = om[((tap * 2) * HH + h) * WW + m];
        float dx = om[((tap * 2 + 1) * HH + h) * WW + m];
        float mv = om[((18 + tap) * HH + h) * WW + m];
        float py = dy + (float)(tap / 3) + (float)(h - 1);
        float px = dx + (float)(tap % 3) + (float)(m - 1);
        float y0f = floorf(py), x0f = floorf(px);
        float ly = py - y0f, lx = px - x0f;
        int y0 = (int)y0f, x0 = (int)x0f;
        int   ys[2] = {y0, y0 + 1};
        int   xs[2] = {x0, x0 + 1};
        float wy[2] = {1.f - ly, ly};
        float wx[2] = {1.f - lx, lx};
#pragma unroll
        for (int r = 0; r < 4; ++r) {
            int yy = ys[r >> 1], xx = xs[r & 1];
            bool ok = ((unsigned)yy < HH) && ((unsigned)xx < WW);
            int yc = min(max(yy, 0), HH - 1);
            int xc = min(max(xx, 0), WW - 1);
            SIDX[tap][r][m] = yc * WW + xc;
            SW[tap][r][m] = ok ? (wy[r >> 1] * wx[r & 1] * mv) : 0.f;
        }
    }
    __syncthreads();

    float acc[4][16];
#pragma unroll
    for (int mi = 0; mi < 4; ++mi)
#pragma unroll
        for (int q = 0; q < 16; ++q) acc[mi][q] = 0.f;

    const float* xb = x + (size_t)b * CIN * HH * WW;

    for (int cc = 0; cc < KTOT / KC; ++cc) {  // 64 chunks
        int c0 = cc * 4;
        // stage weight tile [KC][COUT] (coalesced)
        const float* wsrc = wT + (size_t)c0 * 9 * COUT;
        for (int e = t; e < KC * COUT; e += 256)
            ((float*)WTs)[e] = wsrc[e];
        // stage val tile [KC][64] via bilinear gathers
        for (int e = t; e < KC * 64; e += 256) {
            int m = e & 63, kk = e >> 6;
            int cd = kk / 9;
            int tap = kk - cd * 9;
            const float* xp = xb + (size_t)(c0 + cd) * HH * WW;
            float v = 0.f;
#pragma unroll
            for (int r = 0; r < 4; ++r)
                v += xp[SIDX[tap][r][m]] * SW[tap][r][m];
            VAL[kk][m] = v;
        }
        __syncthreads();
        // FMA: 4m x 16n per thread
        for (int kk = 0; kk < KC; ++kk) {
            float4 a4 = *(const float4*)&VAL[kk][i4];
            float av[4] = {a4.x, a4.y, a4.z, a4.w};
#pragma unroll
            for (int q = 0; q < 16; ++q) {
                float wv = WTs[kk][j + 16 * q];  // 16 consecutive banks, 4x broadcast: conflict-free
#pragma unroll
                for (int mi = 0; mi < 4; ++mi)
                    acc[mi][q] += av[mi] * wv;
            }
        }
        __syncthreads();
    }

    // epilogue: out[b][n][h][w]
    size_t outbase = ((size_t)b * COUT) * HH * WW + (size_t)h * WW;
#pragma unroll
    for (int q = 0; q < 16; ++q) {
        int n = j + 16 * q;
        float4 v = make_float4(acc[0][q], acc[1][q], acc[2][q], acc[3][q]);
        *(float4*)&out[outbase + (size_t)n * HH * WW + i4] = v;
    }
}

extern "C" void kernel_launch(void* const* d_in, const int* in_sizes, int n_in,
                              void* d_out, int out_size, void* d_ws, size_t ws_size,
                              hipStream_t stream) {
    const float* x  = (const float*)d_in[0];
    const float* ow = (const float*)d_in[1];
    const float* ob = (const float*)d_in[2];
    const float* mw = (const float*)d_in[3];
    const float* mb = (const float*)d_in[4];
    const float* rw = (const float*)d_in[5];
    float* out = (float*)d_out;
    float* ws = (float*)d_ws;

    float* wT     = ws + WS_WT;
    float* womT   = ws + WS_WOMT;
    float* offmod = ws + WS_OFFMOD;

    k_transpose_w<<<(COUT * KTOT + 255) / 256, 256, 0, stream>>>(rw, wT);
    k_pack_wom<<<(KTOT * 32 + 255) / 256, 256, 0, stream>>>(ow, mw, womT);
    k_offmod<<<dim3(HH, BB), 256, 0, stream>>>(x, womT, ob, mb, offmod);
    k_deform<<<dim3(HH, BB), 256, 0, stream>>>(x, offmod, wT, out);
}

// Round 2
// 710.509 us; speedup vs baseline: 1.4587x; 1.4587x over previous
//
#include <hip/hip_runtime.h>
#include <math.h>

#define BB 8
#define CIN 256
#define COUT 256
#define HH 64
#define WW 64
#define OCM 27          // 18 offset + 9 mod channels
#define KTOT (CIN * 9)  // 2304, reordered tap-major: k = tap*256 + c
#define NKT 72          // K-tiles of 32

typedef unsigned int u32;
typedef unsigned short u16;

// ---------------- ws layout ----------------
// womT   [KTOT][32] f32   at float ofs 0        (73728 f)
// offmod [BB][27][64][64] at float ofs 73728    (884736 f)
// w2     [72][256][32] bf16 after               (589824 u16)
#define WS_WOMT 0
#define WS_OFFMOD 73728
#define WS_W2_F (73728 + 884736)

__device__ __forceinline__ u16 f2bf(float f) {
    u32 u = __float_as_uint(f);
    u32 r = (u + 0x7FFFu + ((u >> 16) & 1u)) >> 16;
    return (u16)r;
}

typedef __attribute__((address_space(1))) const unsigned int* gptr_t;
typedef __attribute__((address_space(3))) unsigned int* lptr_t;
__device__ __forceinline__ void gl2lds16(const void* g, void* l) {
    __builtin_amdgcn_global_load_lds((gptr_t)g, (lptr_t)l, 16, 0, 0);
}

typedef __attribute__((ext_vector_type(8))) short frag;
typedef __attribute__((ext_vector_type(4))) float f4;

// K0: pack offset_w[18][KTOTo] + mod_w[9][KTOTo] -> womT [c*9+tap][32]  (orig k-order)
__global__ void k_pack_wom(const float* __restrict__ ow, const float* __restrict__ mw,
                           float* __restrict__ womT) {
    int t = blockIdx.x * blockDim.x + threadIdx.x;
    if (t >= KTOT * 32) return;
    int k = t >> 5;
    int oc = t & 31;
    float v = 0.f;
    if (oc < 18) v = ow[oc * KTOT + k];
    else if (oc < 27) v = mw[(oc - 18) * KTOT + k];
    womT[t] = v;
}

// K0b: pack reg_w [n][c][tap] -> w2 [kt][n][32] bf16 with k = tap*256 + c
__global__ void k_pack_w2(const float* __restrict__ rw, u16* __restrict__ w2) {
    int o = blockIdx.x * blockDim.x + threadIdx.x;
    if (o >= NKT * COUT * 32) return;
    int kk = o & 31;
    int n = (o >> 5) & 255;
    int kt = o >> 13;
    int k = kt * 32 + kk;
    int tap = k >> 8;
    int c = k & 255;
    w2[o] = f2bf(rw[n * KTOT + c * 9 + tap]);
}

// K1: offset/mod conv (unchanged from round 1; passed).
__global__ __launch_bounds__(256) void k_offmod(
    const float* __restrict__ x, const float* __restrict__ womT,
    const float* __restrict__ ob, const float* __restrict__ mb,
    float* __restrict__ offmod)
{
    const int h = blockIdx.x, b = blockIdx.y;
    const int t = threadIdx.x;
    const int w = t & 63;
    const int cg = __builtin_amdgcn_readfirstlane(t >> 6);

    float acc[OCM];
#pragma unroll
    for (int i = 0; i < OCM; ++i) acc[i] = 0.f;

    const float* xb = x + (size_t)b * CIN * HH * WW;
    for (int ci = 0; ci < 64; ++ci) {
        int c = cg * 64 + ci;
        const float* xc = xb + (size_t)c * HH * WW;
#pragma unroll
        for (int ky = 0; ky < 3; ++ky) {
            int y = h + ky - 1;
            bool yok = (unsigned)y < HH;
            const float* xr = xc + y * WW;
            const float* wp = womT + (size_t)(c * 9 + ky * 3) * 32;
#pragma unroll
            for (int kx = 0; kx < 3; ++kx) {
                int xx = w + kx - 1;
                float xv = (yok && (unsigned)xx < WW) ? xr[xx] : 0.f;
#pragma unroll
                for (int oc = 0; oc < OCM; ++oc)
                    acc[oc] += xv * wp[kx * 32 + oc];
            }
        }
    }

    __shared__ float red[4][OCM][64];
#pragma unroll
    for (int i = 0; i < OCM; ++i) red[cg][i][w] = acc[i];
    __syncthreads();

    for (int r = t; r < OCM * 64; r += 256) {
        int oc = r >> 6;
        int ww = r & 63;
        float s = red[0][oc][ww] + red[1][oc][ww] + red[2][oc][ww] + red[3][oc][ww];
        float outv;
        if (oc < 18) {
            s += ob[oc];
            outv = fminf(fmaxf(s, -16.f), 16.f);
        } else {
            outv = 1.f / (1.f + __expf(-(s + mb[oc - 18])));
        }
        offmod[(((size_t)b * OCM + oc) * HH + h) * WW + ww] = outv;
    }
}

// K2: fused gather + bf16-MFMA GEMM.
// grid (32 mtiles, 2 ntiles, 8 b); block 256 thr = 4 waves (2x2 of 64x64).
// M-tile = 128 hw (2 rows), N-tile = 128 cout, K = 2304 tap-major, BK = 32.
__global__ __launch_bounds__(256) void k_deform2(
    const float* __restrict__ x, const float* __restrict__ offmod,
    const u16* __restrict__ w2, float* __restrict__ out)
{
    const int t = threadIdx.x;
    const int m0 = blockIdx.x * 128;
    const int n0 = blockIdx.y * 128;
    const int b  = blockIdx.z;
    const int h0 = m0 >> 6;

    __shared__ int   SIDX[9][4][128];
    __shared__ float SW[9][4][128];
    __shared__ u16   As[128 * 32];
    __shared__ u16   Bs[128 * 32];

    // ---- build per-block sample tables: 9 taps x 128 m ----
    const float* om = offmod + (size_t)b * OCM * HH * WW;
    for (int e = t; e < 9 * 128; e += 256) {
        int m = e & 127, tap = e >> 7;
        int h = h0 + (m >> 6), w = m & 63;
        float dy = om[(tap * 2) * 4096 + h * 64 + w];
        float dx = om[(tap * 2 + 1) * 4096 + h * 64 + w];
        float mv = om[(18 + tap) * 4096 + h * 64 + w];
        float py = dy + (float)(tap / 3) + (float)(h - 1);
        float px = dx + (float)(tap % 3) + (float)(w - 1);
        float y0f = floorf(py), x0f = floorf(px);
        float ly = py - y0f, lx = px - x0f;
        int y0 = (int)y0f, x0 = (int)x0f;
        int   ys[2] = {y0, y0 + 1};
        int   xs[2] = {x0, x0 + 1};
        float wy[2] = {1.f - ly, ly};
        float wx[2] = {1.f - lx, lx};
#pragma unroll
        for (int r = 0; r < 4; ++r) {
            int yy = ys[r >> 1], xx = xs[r & 1];
            bool ok = ((unsigned)yy < HH) && ((unsigned)xx < WW);
            int yc = min(max(yy, 0), HH - 1);
            int xc = min(max(xx, 0), WW - 1);
            SIDX[tap][r][m] = yc * WW + xc;
            SW[tap][r][m] = ok ? (wy[r >> 1] * wx[r & 1] * mv) : 0.f;
        }
    }
    __syncthreads();

    const int lane = t & 63, wv = t >> 6;
    const int wm = (wv & 1) * 64, wn = (wv >> 1) * 64;
    const int fr = lane & 15, q = lane >> 4;

    f4 acc[4][4];
#pragma unroll
    for (int mi = 0; mi < 4; ++mi)
#pragma unroll
        for (int ni = 0; ni < 4; ++ni) acc[mi][ni] = (f4){0.f, 0.f, 0.f, 0.f};

    for (int kt = 0; kt < NKT; ++kt) {
        // ---- stage B tile [128 n][32 k] bf16 via global_load_lds (8 KB) ----
        const u16* bsrc = w2 + ((size_t)kt * COUT + n0) * 32;
        gl2lds16(bsrc + (size_t)t * 8, &Bs[t * 8]);
        gl2lds16(bsrc + (size_t)(256 + t) * 8, &Bs[(256 + t) * 8]);

        // ---- gather A tile [128 m][32 k]: 2 units of (m, k-octet) per thread ----
#pragma unroll
        for (int uu = 0; uu < 2; ++uu) {
            int u = t + uu * 256;
            int m = u & 127, oct = u >> 7;
            int kg = kt * 32 + oct * 8;
            int tap = kg >> 8;     // tap-major k: same tap for whole octet
            int c0 = kg & 255;
            int i0 = SIDX[tap][0][m], i1 = SIDX[tap][1][m],
                i2 = SIDX[tap][2][m], i3 = SIDX[tap][3][m];
            float s0 = SW[tap][0][m], s1 = SW[tap][1][m],
                  s2 = SW[tap][2][m], s3 = SW[tap][3][m];
            u32 base = ((u32)b * CIN + (u32)c0) * 4096u;
            u32 o0 = base + i0, o1 = base + i1, o2 = base + i2, o3 = base + i3;
            u32 pk[4];
#pragma unroll
            for (int jp = 0; jp < 4; ++jp) {
                float va = x[o0] * s0 + x[o1] * s1 + x[o2] * s2 + x[o3] * s3;
                o0 += 4096; o1 += 4096; o2 += 4096; o3 += 4096;
                float vb = x[o0] * s0 + x[o1] * s1 + x[o2] * s2 + x[o3] * s3;
                o0 += 4096; o1 += 4096; o2 += 4096; o3 += 4096;
                pk[jp] = (u32)f2bf(va) | ((u32)f2bf(vb) << 16);
            }
            *(uint4*)&As[m * 32 + oct * 8] = make_uint4(pk[0], pk[1], pk[2], pk[3]);
        }
        __syncthreads();

        // ---- MFMA: each wave 64x64 = 4x4 frags of 16x16x32 ----
        frag a[4], bf[4];
#pragma unroll
        for (int mi = 0; mi < 4; ++mi)
            a[mi] = *(const frag*)&As[(wm + mi * 16 + fr) * 32 + q * 8];
#pragma unroll
        for (int ni = 0; ni < 4; ++ni)
            bf[ni] = *(const frag*)&Bs[(wn + ni * 16 + fr) * 32 + q * 8];
#pragma unroll
        for (int mi = 0; mi < 4; ++mi)
#pragma unroll
            for (int ni = 0; ni < 4; ++ni)
                acc[mi][ni] = __builtin_amdgcn_mfma_f32_16x16x32_bf16(
                    a[mi], bf[ni], acc[mi][ni], 0, 0, 0);
        __syncthreads();
    }

    // ---- epilogue: out[b][n][hw], C/D layout col=lane&15(n), row=(lane>>4)*4+r(m) ----
#pragma unroll
    for (int mi = 0; mi < 4; ++mi)
#pragma unroll
        for (int ni = 0; ni < 4; ++ni) {
            int n_g = n0 + wn + ni * 16 + fr;
            int m_g = m0 + wm + mi * 16 + q * 4;
            float4 v = make_float4(acc[mi][ni][0], acc[mi][ni][1],
                                   acc[mi][ni][2], acc[mi][ni][3]);
            *(float4*)&out[((size_t)b * COUT + n_g) * 4096 + m_g] = v;
        }
}

extern "C" void kernel_launch(void* const* d_in, const int* in_sizes, int n_in,
                              void* d_out, int out_size, void* d_ws, size_t ws_size,
                              hipStream_t stream) {
    const float* x  = (const float*)d_in[0];
    const float* ow = (const float*)d_in[1];
    const float* ob = (const float*)d_in[2];
    const float* mw = (const float*)d_in[3];
    const float* mb = (const float*)d_in[4];
    const float* rw = (const float*)d_in[5];
    float* out = (float*)d_out;
    float* ws = (float*)d_ws;

    float* womT   = ws + WS_WOMT;
    float* offmod = ws + WS_OFFMOD;
    u16*   w2     = (u16*)(ws + WS_W2_F);

    k_pack_wom<<<(KTOT * 32 + 255) / 256, 256, 0, stream>>>(ow, mw, womT);
    k_pack_w2<<<(NKT * COUT * 32 + 255) / 256, 256, 0, stream>>>(rw, w2);
    k_offmod<<<dim3(HH, BB), 256, 0, stream>>>(x, womT, ob, mb, offmod);
    k_deform2<<<dim3(32, 2, BB), 256, 0, stream>>>(x, offmod, w2, out);
}

// Round 3
// 244.080 us; speedup vs baseline: 4.2461x; 2.9110x over previous
//
#include <hip/hip_runtime.h>
#include <math.h>

#define BB 8
#define CIN 256
#define COUT 256
#define HH 64
#define WW 64
#define OCM 27          // 18 offset + 9 mod channels
#define KTOT 2304       // reordered tap-major: k = tap*256 + c
#define NKT 72          // K-tiles of 32

typedef unsigned int u32;
typedef unsigned short u16;

// ---------------- ws layout (bytes) ----------------
// xbf    [8][64][64][256] bf16 NHWC   at 0           (16,777,216 B)
// w2     [72][256][32]    bf16        at 16777216    ( 1,179,648 B)
// w2om   [72][32][32]     bf16        at 17956864    (   147,456 B)
// offmod [8][27][4096]    f32         at 18104320    ( 3,538,944 B)
#define WS_XBF 0
#define WS_W2 16777216
#define WS_W2OM 17956864
#define WS_OFFMOD 18104320

__device__ __forceinline__ u16 f2bf(float f) {
    u32 u = __float_as_uint(f);
    u32 r = (u + 0x7FFFu + ((u >> 16) & 1u)) >> 16;
    return (u16)r;
}

typedef __attribute__((ext_vector_type(8))) short frag;
typedef __attribute__((ext_vector_type(4))) float f4;

// K0: NCHW f32 -> NHWC bf16. block=(y,b), 256 thr = 256 c.
__global__ __launch_bounds__(256) void k_nhwc(const float* __restrict__ x,
                                              u16* __restrict__ xbf) {
    const int y = blockIdx.x, b = blockIdx.y;
    const int c = threadIdx.x;
    const float* xp = x + ((size_t)b * CIN + c) * 4096 + y * 64;
    u16* op = xbf + ((size_t)b * 4096 + y * 64) * 256 + c;
    for (int w4 = 0; w4 < 16; ++w4) {
        float4 v = *(const float4*)&xp[w4 * 4];
        op[(w4 * 4 + 0) * 256] = f2bf(v.x);
        op[(w4 * 4 + 1) * 256] = f2bf(v.y);
        op[(w4 * 4 + 2) * 256] = f2bf(v.z);
        op[(w4 * 4 + 3) * 256] = f2bf(v.w);
    }
}

// K0b: reg_w [n][c][tap] -> w2 [kt][n][32] bf16, k = tap*256 + c
__global__ void k_pack_w2(const float* __restrict__ rw, u16* __restrict__ w2) {
    int o = blockIdx.x * blockDim.x + threadIdx.x;
    if (o >= NKT * COUT * 32) return;
    int kk = o & 31;
    int n = (o >> 5) & 255;
    int kt = o >> 13;
    int k = kt * 32 + kk;
    int tap = k >> 8;
    int c = k & 255;
    w2[o] = f2bf(rw[n * KTOT + c * 9 + tap]);
}

// K0c: offset_w/mod_w -> w2om [kt][32 oc][32 kk] bf16, k = tap*256 + c
__global__ void k_pack_w2om(const float* __restrict__ ow, const float* __restrict__ mw,
                            u16* __restrict__ w2om) {
    int o = blockIdx.x * blockDim.x + threadIdx.x;
    if (o >= NKT * 32 * 32) return;
    int kk = o & 31;
    int oc = (o >> 5) & 31;
    int kt = o >> 10;
    int k = kt * 32 + kk;
    int tap = k >> 8;
    int c = k & 255;
    float v = 0.f;
    if (oc < 18) v = ow[oc * KTOT + c * 9 + tap];
    else if (oc < 27) v = mw[(oc - 18) * KTOT + c * 9 + tap];
    w2om[o] = f2bf(v);
}

// K1: offset/mod conv via MFMA. block covers 128 m (2 rows) x 32 n; grid (32,8).
__global__ __launch_bounds__(256) void k_offmod3(
    const u16* __restrict__ xbf, const u16* __restrict__ w2om,
    const float* __restrict__ ob, const float* __restrict__ mb,
    float* __restrict__ offmod)
{
    const int t = threadIdx.x;
    const int b = blockIdx.y;
    const int y0 = blockIdx.x * 2;

    __shared__ u16 As[128 * 40];
    __shared__ u16 Bs[32 * 40];

    const int lane = t & 63, wv = t >> 6;
    const int wm = wv * 32;
    const int fr = lane & 15, q = lane >> 4;

    const int m_s = t >> 1, half = t & 1;
    const int ys = y0 + (m_s >> 6), xs = m_s & 63;

    f4 acc[2][2];
#pragma unroll
    for (int mi = 0; mi < 2; ++mi)
#pragma unroll
        for (int ni = 0; ni < 2; ++ni) acc[mi][ni] = (f4){0.f, 0.f, 0.f, 0.f};

    for (int kt = 0; kt < NKT; ++kt) {
        const int tap = kt >> 3;
        const int ty = tap / 3 - 1, tx = tap % 3 - 1;
        const int c0 = (kt & 7) * 32 + half * 16;
        // stage B tile [32 n][32 kk] -> pad-40 (threads 0..127)
        if (t < 128) {
            int n = t >> 2, ko = t & 3;
            uint4 v = *(const uint4*)(w2om + (size_t)kt * 1024 + n * 32 + ko * 8);
            *(uint4*)&Bs[n * 40 + ko * 8] = v;
        }
        // stage A tile [128 m][32 kk] -> pad-40
        int yy = ys + ty, xx = xs + tx;
        uint4 v0 = make_uint4(0, 0, 0, 0), v1 = make_uint4(0, 0, 0, 0);
        if ((unsigned)yy < HH && (unsigned)xx < WW) {
            const uint4* p = (const uint4*)(xbf + (((size_t)b * 4096 + yy * 64 + xx) * 256 + c0));
            v0 = p[0]; v1 = p[1];
        }
        *(uint4*)&As[m_s * 40 + half * 16] = v0;
        *(uint4*)&As[m_s * 40 + half * 16 + 8] = v1;
        __syncthreads();

        frag a0 = *(const frag*)&As[(wm + fr) * 40 + q * 8];
        frag a1 = *(const frag*)&As[(wm + 16 + fr) * 40 + q * 8];
        frag b0 = *(const frag*)&Bs[fr * 40 + q * 8];
        frag b1 = *(const frag*)&Bs[(16 + fr) * 40 + q * 8];
        acc[0][0] = __builtin_amdgcn_mfma_f32_16x16x32_bf16(a0, b0, acc[0][0], 0, 0, 0);
        acc[0][1] = __builtin_amdgcn_mfma_f32_16x16x32_bf16(a0, b1, acc[0][1], 0, 0, 0);
        acc[1][0] = __builtin_amdgcn_mfma_f32_16x16x32_bf16(a1, b0, acc[1][0], 0, 0, 0);
        acc[1][1] = __builtin_amdgcn_mfma_f32_16x16x32_bf16(a1, b1, acc[1][1], 0, 0, 0);
        __syncthreads();
    }

    // epilogue: C/D col=fr(n=oc), row=q*4+r (m). clip / sigmoid, write planes.
#pragma unroll
    for (int ni = 0; ni < 2; ++ni) {
        int oc = ni * 16 + fr;
        if (oc >= OCM) continue;
        bool is_off = oc < 18;
        float bias = is_off ? ob[oc] : mb[oc - 18];
#pragma unroll
        for (int mi = 0; mi < 2; ++mi) {
            int m_l = wm + mi * 16 + q * 4;
            float4 v;
            float* vp = (float*)&v;
#pragma unroll
            for (int r = 0; r < 4; ++r) {
                float s = acc[mi][ni][r] + bias;
                vp[r] = is_off ? fminf(fmaxf(s, -16.f), 16.f)
                               : 1.f / (1.f + __expf(-s));
            }
            *(float4*)&offmod[((size_t)b * OCM + oc) * 4096 + y0 * 64 + m_l] = v;
        }
    }
}

// K2: deformable conv, NHWC bf16 gather + MFMA. block = 64 m (one h-row) x 256 n.
// grid (64 h, 8 b); 256 thr = 4 waves (2m x 2n of 32x128).
__global__ __launch_bounds__(256) void k_deform3(
    const u16* __restrict__ xbf, const float* __restrict__ offmod,
    const u16* __restrict__ w2, float* __restrict__ out)
{
    const int t = threadIdx.x;
    const int h = blockIdx.x, b = blockIdx.y;

    __shared__ int   SIDX[9][4][64];
    __shared__ float SW[9][4][64];
    __shared__ u16 As[64 * 40];
    __shared__ u16 Bs[256 * 40];

    // ---- sample tables: 9 taps x 64 w ----
    const float* om = offmod + (size_t)b * OCM * 4096;
    for (int e = t; e < 9 * 64; e += 256) {
        int m = e & 63, tap = e >> 6;
        float dy = om[(tap * 2) * 4096 + h * 64 + m];
        float dx = om[(tap * 2 + 1) * 4096 + h * 64 + m];
        float mv = om[(18 + tap) * 4096 + h * 64 + m];
        float py = dy + (float)(tap / 3) + (float)(h - 1);
        float px = dx + (float)(tap % 3) + (float)(m - 1);
        float y0f = floorf(py), x0f = floorf(px);
        float ly = py - y0f, lx = px - x0f;
        int y0 = (int)y0f, x0 = (int)x0f;
        int   ysr[2] = {y0, y0 + 1};
        int   xsr[2] = {x0, x0 + 1};
        float wy[2] = {1.f - ly, ly};
        float wx[2] = {1.f - lx, lx};
#pragma unroll
        for (int r = 0; r < 4; ++r) {
            int yy = ysr[r >> 1], xx = xsr[r & 1];
            bool ok = ((unsigned)yy < HH) && ((unsigned)xx < WW);
            int yc = min(max(yy, 0), HH - 1);
            int xc = min(max(xx, 0), WW - 1);
            SIDX[tap][r][m] = yc * WW + xc;
            SW[tap][r][m] = ok ? (wy[r >> 1] * wx[r & 1] * mv) : 0.f;
        }
    }
    __syncthreads();

    const int lane = t & 63, wv = t >> 6;
    const int wm = (wv & 1) * 32, wn = (wv >> 1) * 128;
    const int fr = lane & 15, q = lane >> 4;
    const int m_g = t >> 2, oct = t & 3;
    const u16* xpl = xbf + (size_t)b * 4096 * 256;

    f4 acc[2][8];
#pragma unroll
    for (int mi = 0; mi < 2; ++mi)
#pragma unroll
        for (int ni = 0; ni < 8; ++ni) acc[mi][ni] = (f4){0.f, 0.f, 0.f, 0.f};

    for (int kt = 0; kt < NKT; ++kt) {
        const int tap = kt >> 3;
        const int c0 = (kt & 7) * 32 + oct * 8;
        // ---- stage B tile [256 n][32 kk] -> pad-40 (coalesced uint4) ----
        const u16* bsrc = w2 + (size_t)kt * 8192;
#pragma unroll
        for (int p = 0; p < 4; ++p) {
            int chunk = t + p * 256;
            int n = chunk >> 2, ko = chunk & 3;
            uint4 v = *(const uint4*)(bsrc + n * 32 + ko * 8);
            *(uint4*)&Bs[n * 40 + ko * 8] = v;
        }
        // ---- gather A: unit (m_g, oct) = 8 channels, 4 corners x 16 B ----
        int   i0 = SIDX[tap][0][m_g], i1 = SIDX[tap][1][m_g],
              i2 = SIDX[tap][2][m_g], i3 = SIDX[tap][3][m_g];
        float s0 = SW[tap][0][m_g], s1 = SW[tap][1][m_g],
              s2 = SW[tap][2][m_g], s3 = SW[tap][3][m_g];
        float va[8];
#pragma unroll
        for (int j = 0; j < 8; ++j) va[j] = 0.f;
        int   idx[4] = {i0, i1, i2, i3};
        float sws[4] = {s0, s1, s2, s3};
#pragma unroll
        for (int r = 0; r < 4; ++r) {
            uint4 cv = *(const uint4*)(xpl + (size_t)idx[r] * 256 + c0);
            float s = sws[r];
            u32 uu[4] = {cv.x, cv.y, cv.z, cv.w};
#pragma unroll
            for (int jj = 0; jj < 4; ++jj) {
                va[2 * jj]     += s * __uint_as_float(uu[jj] << 16);
                va[2 * jj + 1] += s * __uint_as_float(uu[jj] & 0xFFFF0000u);
            }
        }
        u32 pk[4];
#pragma unroll
        for (int jp = 0; jp < 4; ++jp)
            pk[jp] = (u32)f2bf(va[2 * jp]) | ((u32)f2bf(va[2 * jp + 1]) << 16);
        *(uint4*)&As[m_g * 40 + oct * 8] = make_uint4(pk[0], pk[1], pk[2], pk[3]);
        __syncthreads();

        // ---- MFMA: wave 32m x 128n = 2x8 frags ----
        frag a[2], bfr[8];
#pragma unroll
        for (int mi = 0; mi < 2; ++mi)
            a[mi] = *(const frag*)&As[(wm + mi * 16 + fr) * 40 + q * 8];
#pragma unroll
        for (int ni = 0; ni < 8; ++ni)
            bfr[ni] = *(const frag*)&Bs[(wn + ni * 16 + fr) * 40 + q * 8];
#pragma unroll
        for (int mi = 0; mi < 2; ++mi)
#pragma unroll
            for (int ni = 0; ni < 8; ++ni)
                acc[mi][ni] = __builtin_amdgcn_mfma_f32_16x16x32_bf16(
                    a[mi], bfr[ni], acc[mi][ni], 0, 0, 0);
        __syncthreads();
    }

    // ---- epilogue: out[b][n][h*64+w] ----
#pragma unroll
    for (int ni = 0; ni < 8; ++ni) {
        int n_g = wn + ni * 16 + fr;
        float* outn = out + ((size_t)b * COUT + n_g) * 4096 + h * 64;
#pragma unroll
        for (int mi = 0; mi < 2; ++mi) {
            int wl = wm + mi * 16 + q * 4;
            *(float4*)&outn[wl] = make_float4(acc[mi][ni][0], acc[mi][ni][1],
                                              acc[mi][ni][2], acc[mi][ni][3]);
        }
    }
}

extern "C" void kernel_launch(void* const* d_in, const int* in_sizes, int n_in,
                              void* d_out, int out_size, void* d_ws, size_t ws_size,
                              hipStream_t stream) {
    const float* x  = (const float*)d_in[0];
    const float* ow = (const float*)d_in[1];
    const float* ob = (const float*)d_in[2];
    const float* mw = (const float*)d_in[3];
    const float* mb = (const float*)d_in[4];
    const float* rw = (const float*)d_in[5];
    float* out = (float*)d_out;
    char* ws = (char*)d_ws;

    u16*   xbf    = (u16*)(ws + WS_XBF);
    u16*   w2     = (u16*)(ws + WS_W2);
    u16*   w2om   = (u16*)(ws + WS_W2OM);
    float* offmod = (float*)(ws + WS_OFFMOD);

    k_nhwc<<<dim3(HH, BB), 256, 0, stream>>>(x, xbf);
    k_pack_w2<<<(NKT * COUT * 32 + 255) / 256, 256, 0, stream>>>(rw, w2);
    k_pack_w2om<<<(NKT * 32 * 32 + 255) / 256, 256, 0, stream>>>(ow, mw, w2om);
    k_offmod3<<<dim3(32, BB), 256, 0, stream>>>(xbf, w2om, ob, mb, offmod);
    k_deform3<<<dim3(HH, BB), 256, 0, stream>>>(xbf, offmod, w2, out);
}

// Round 4
// 208.255 us; speedup vs baseline: 4.9766x; 1.1720x over previous
//
#include <hip/hip_runtime.h>
#include <math.h>

#define BB 8
#define CIN 256
#define COUT 256
#define HH 64
#define WW 64
#define OCM 27          // 18 offset + 9 mod channels
#define KTOT 2304       // tap-major: k = tap*256 + c
#define NKT 72          // K-tiles of 32

typedef unsigned int u32;
typedef unsigned short u16;

// ---------------- ws layout (bytes) ----------------
// xbf    [8][64][64][256] bf16 NHWC   at 0           (16,777,216 B)
// w2     [72][256][32]    bf16        at 16777216    ( 1,179,648 B)
// w2om   [72][32][32]     bf16        at 17956864    (   147,456 B)
// offmod [8][27][4096]    f32         at 18104320    ( 3,538,944 B)
#define WS_XBF 0
#define WS_W2 16777216
#define WS_W2OM 17956864
#define WS_OFFMOD 18104320

__device__ __forceinline__ u16 f2bf(float f) {
    u32 u = __float_as_uint(f);
    u32 r = (u + 0x7FFFu + ((u >> 16) & 1u)) >> 16;
    return (u16)r;
}

typedef __attribute__((address_space(1))) const unsigned int* gptr_t;
typedef __attribute__((address_space(3))) unsigned int* lptr_t;
__device__ __forceinline__ void gl2lds16(const void* g, void* l) {
    __builtin_amdgcn_global_load_lds((gptr_t)g, (lptr_t)l, 16, 0, 0);
}

typedef __attribute__((ext_vector_type(8))) short frag;
typedef __attribute__((ext_vector_type(4))) float f4;

// XOR-octet swizzle: octet o (8 u16) of row r at r*32 + (o^(r&3))*8.
// Both staging writes and MFMA frag reads hit all 32 banks per 8 lanes.
__device__ __forceinline__ int sw_off(int row, int oct) {
    return (row << 5) + ((oct ^ (row & 3)) << 3);
}

#define BARRIER_RAW() do { asm volatile("" ::: "memory"); \
    __builtin_amdgcn_s_barrier(); asm volatile("" ::: "memory"); } while (0)

// K0: NCHW f32 -> NHWC bf16 via LDS transpose (coalesced both sides).
__global__ __launch_bounds__(256) void k_nhwc2(const float* __restrict__ x,
                                               u16* __restrict__ xbf) {
    const int y = blockIdx.x, b = blockIdx.y;
    __shared__ float T[64][65];
    const int wl = threadIdx.x & 63, g = threadIdx.x >> 6;
    for (int c0 = 0; c0 < 256; c0 += 64) {
#pragma unroll
        for (int i = 0; i < 16; ++i) {
            int c = g + i * 4;
            T[c][wl] = x[(((size_t)(b * 256 + c0 + c)) << 12) + (y << 6) + wl];
        }
        __syncthreads();
#pragma unroll
        for (int j = 0; j < 16; ++j) {
            int w = g * 16 + j;
            xbf[((((size_t)b << 12) + (y << 6) + w) << 8) + c0 + wl] = f2bf(T[wl][w]);
        }
        __syncthreads();
    }
}

// K0b: reg_w [n][c][tap] -> w2 [kt][n][32] bf16, k = tap*256 + c
__global__ void k_pack_w2(const float* __restrict__ rw, u16* __restrict__ w2) {
    int o = blockIdx.x * blockDim.x + threadIdx.x;
    if (o >= NKT * COUT * 32) return;
    int kk = o & 31;
    int n = (o >> 5) & 255;
    int kt = o >> 13;
    int k = kt * 32 + kk;
    int tap = k >> 8;
    int c = k & 255;
    w2[o] = f2bf(rw[n * KTOT + c * 9 + tap]);
}

// K0c: offset_w/mod_w -> w2om [kt][32 oc][32 kk] bf16
__global__ void k_pack_w2om(const float* __restrict__ ow, const float* __restrict__ mw,
                            u16* __restrict__ w2om) {
    int o = blockIdx.x * blockDim.x + threadIdx.x;
    if (o >= NKT * 32 * 32) return;
    int kk = o & 31;
    int oc = (o >> 5) & 31;
    int kt = o >> 10;
    int k = kt * 32 + kk;
    int tap = k >> 8;
    int c = k & 255;
    float v = 0.f;
    if (oc < 18) v = ow[oc * KTOT + c * 9 + tap];
    else if (oc < 27) v = mw[(oc - 18) * KTOT + c * 9 + tap];
    w2om[o] = f2bf(v);
}

// K1: offset/mod conv, pipelined MFMA. block = (h,b): 64m(w) x 32n, BK=32.
__global__ __launch_bounds__(256) void k_offmod4(
    const u16* __restrict__ xbf, const u16* __restrict__ w2om,
    const float* __restrict__ ob, const float* __restrict__ mb,
    float* __restrict__ offmod)
{
    const int h = blockIdx.x, b = blockIdx.y;
    const int t = threadIdx.x;
    const int lane = t & 63, wv = t >> 6;
    const int fr = lane & 15, q = lane >> 4;
    const int wm = wv * 16;
    const int mg = t >> 2, oct = t & 3;   // A staging unit

    __shared__ u16 AsB[2][64 * 32];
    __shared__ u16 BsB[2][32 * 32];

    const u16* xb = xbf + ((size_t)b << 20);

    auto loadA = [&](int kt, uint4* r) {
        int tap = kt >> 3;
        int yy = h + tap / 3 - 1, xx = mg + tap % 3 - 1;
        int c0 = ((kt & 7) << 5) + (oct << 3);
        uint4 v = make_uint4(0, 0, 0, 0);
        if ((unsigned)yy < HH && (unsigned)xx < WW)
            v = *(const uint4*)(xb + (((size_t)yy << 6) + xx) * 256 + c0);
        *r = v;
    };
    auto loadB = [&](int kt, uint4* r) {
        if (t < 128) *r = *(const uint4*)(w2om + (size_t)kt * 1024 + (t >> 2) * 32 + (t & 3) * 8);
    };
    auto storeAB = [&](int buf, uint4* rA, uint4* rB) {
        *(uint4*)&AsB[buf][sw_off(mg, oct)] = *rA;
        if (t < 128) *(uint4*)&BsB[buf][sw_off(t >> 2, t & 3)] = *rB;
    };

    f4 acc[2];
    acc[0] = (f4){0.f, 0.f, 0.f, 0.f};
    acc[1] = (f4){0.f, 0.f, 0.f, 0.f};

    uint4 rA0, rB0, rA1, rB1;
    // prologue: tile 0 into buf0; prefetch tile 1 into regs
    loadA(0, &rA0); loadB(0, &rB0);
    storeAB(0, &rA0, &rB0);
    loadA(1, &rA1); loadB(1, &rB1);
    asm volatile("s_waitcnt lgkmcnt(0)" ::: "memory");

    auto body = [&](int kt, int p, uint4* cA, uint4* cB, uint4* nA, uint4* nB) {
        BARRIER_RAW();
        frag a  = *(const frag*)&AsB[p][sw_off(wm + fr, q)];
        frag b0 = *(const frag*)&BsB[p][sw_off(fr, q)];
        frag b1 = *(const frag*)&BsB[p][sw_off(16 + fr, q)];
        if (kt + 2 < NKT) { loadA(kt + 2, nA); loadB(kt + 2, nB); }
        if (kt + 1 < NKT) storeAB(1 - p, cA, cB);
        acc[0] = __builtin_amdgcn_mfma_f32_16x16x32_bf16(a, b0, acc[0], 0, 0, 0);
        acc[1] = __builtin_amdgcn_mfma_f32_16x16x32_bf16(a, b1, acc[1], 0, 0, 0);
        asm volatile("s_waitcnt lgkmcnt(0)" ::: "memory");
    };
    for (int kt = 0; kt < NKT; kt += 2) {
        body(kt, 0, &rA1, &rB1, &rA0, &rB0);
        body(kt + 1, 1, &rA0, &rB0, &rA1, &rB1);
    }

    // epilogue: col = fr -> oc, row = q*4+r -> w within wave's 16
#pragma unroll
    for (int ni = 0; ni < 2; ++ni) {
        int oc = ni * 16 + fr;
        if (oc >= OCM) continue;
        bool is_off = oc < 18;
        float bias = is_off ? ob[oc] : mb[oc - 18];
        float4 v;
        float* vp = (float*)&v;
#pragma unroll
        for (int r = 0; r < 4; ++r) {
            float s = acc[ni][r] + bias;
            vp[r] = is_off ? fminf(fmaxf(s, -16.f), 16.f)
                           : 1.f / (1.f + __expf(-s));
        }
        *(float4*)&offmod[(((size_t)b * OCM + oc) << 12) + (h << 6) + wm + q * 4] = v;
    }
}

// K2: deformable conv, pipelined gather + MFMA.
// block = (h,b): 64m x 256n, BK=32; 4 waves each 64m x 64n.
__global__ __launch_bounds__(256) void k_deform4(
    const u16* __restrict__ xbf, const float* __restrict__ offmod,
    const u16* __restrict__ w2, float* __restrict__ out)
{
    const int t = threadIdx.x;
    const int h = blockIdx.x, b = blockIdx.y;
    const int lane = t & 63, wv = t >> 6;
    const int fr = lane & 15, q = lane >> 4;
    const int wn = wv * 64;
    const int mg = t >> 2, oct = t & 3;   // gather unit

    __shared__ int   SIDX[9][4][64];
    __shared__ float SW[9][4][64];
    __shared__ u16 AsB[2][64 * 32];
    __shared__ u16 BsB[2][256 * 32];

    // ---- sample tables: 9 taps x 64 w ----
    const float* om = offmod + (size_t)b * OCM * 4096;
    for (int e = t; e < 9 * 64; e += 256) {
        int m = e & 63, tap = e >> 6;
        float dy = om[(tap * 2) * 4096 + h * 64 + m];
        float dx = om[(tap * 2 + 1) * 4096 + h * 64 + m];
        float mv = om[(18 + tap) * 4096 + h * 64 + m];
        float py = dy + (float)(tap / 3) + (float)(h - 1);
        float px = dx + (float)(tap % 3) + (float)(m - 1);
        float y0f = floorf(py), x0f = floorf(px);
        float ly = py - y0f, lx = px - x0f;
        int y0 = (int)y0f, x0 = (int)x0f;
        int   ysr[2] = {y0, y0 + 1};
        int   xsr[2] = {x0, x0 + 1};
        float wy[2] = {1.f - ly, ly};
        float wx[2] = {1.f - lx, lx};
#pragma unroll
        for (int r = 0; r < 4; ++r) {
            int yy = ysr[r >> 1], xx = xsr[r & 1];
            bool ok = ((unsigned)yy < HH) && ((unsigned)xx < WW);
            int yc = min(max(yy, 0), HH - 1);
            int xc = min(max(xx, 0), WW - 1);
            SIDX[tap][r][m] = yc * WW + xc;
            SW[tap][r][m] = ok ? (wy[r >> 1] * wx[r & 1] * mv) : 0.f;
        }
    }
    __syncthreads();

    const u16* xpl = xbf + ((size_t)b << 20);
    const int ko_sw = (lane & 3) ^ ((lane >> 2) & 3);  // gl2lds source-octet permute

    auto stageB = [&](int kt, int buf) {
        const u16* src = w2 + ((size_t)kt << 13);
#pragma unroll
        for (int j = 0; j < 4; ++j) {
            int n = (wv << 6) + (j << 4) + (lane >> 2);
            u16* dst = &BsB[buf][((wv << 6) + (j << 4)) << 5];  // wave-uniform base
            gl2lds16(src + n * 32 + ko_sw * 8, dst);
        }
    };
    auto loadCorners = [&](int kt, uint4* cr) {
        int tap = kt >> 3;
        int c0 = ((kt & 7) << 5) + (oct << 3);
        const u16* base = xpl + c0;
#pragma unroll
        for (int r = 0; r < 4; ++r)
            cr[r] = *(const uint4*)(base + ((size_t)SIDX[tap][r][mg] << 8));
    };
    auto interpStore = [&](int kt, int buf, uint4* cr) {
        int tap = kt >> 3;
        float va[8];
#pragma unroll
        for (int j = 0; j < 8; ++j) va[j] = 0.f;
#pragma unroll
        for (int r = 0; r < 4; ++r) {
            float s = SW[tap][r][mg];
            u32 uu[4] = {cr[r].x, cr[r].y, cr[r].z, cr[r].w};
#pragma unroll
            for (int jj = 0; jj < 4; ++jj) {
                va[2 * jj]     += s * __uint_as_float(uu[jj] << 16);
                va[2 * jj + 1] += s * __uint_as_float(uu[jj] & 0xFFFF0000u);
            }
        }
        u32 pk[4];
#pragma unroll
        for (int jp = 0; jp < 4; ++jp)
            pk[jp] = (u32)f2bf(va[2 * jp]) | ((u32)f2bf(va[2 * jp + 1]) << 16);
        *(uint4*)&AsB[buf][sw_off(mg, oct)] = make_uint4(pk[0], pk[1], pk[2], pk[3]);
    };

    f4 acc[4][4];
#pragma unroll
    for (int mi = 0; mi < 4; ++mi)
#pragma unroll
        for (int ni = 0; ni < 4; ++ni) acc[mi][ni] = (f4){0.f, 0.f, 0.f, 0.f};

    uint4 crA[4], crB[4];
    // prologue: B(0)->Bs0, corners(0)->crB, B(1)->Bs1, corners(1)->crA,
    // interp(0)->As0 (drains B0/c0, keeps B1/c1 in flight)
    stageB(0, 0);
    loadCorners(0, crB);
    stageB(1, 1);
    loadCorners(1, crA);
    interpStore(0, 0, crB);
    asm volatile("s_waitcnt lgkmcnt(0)" ::: "memory");

    auto body = [&](int kt, int p, uint4* cur, uint4* nxt) {
        // B(kt) must be landed; corners(kt+1) may stay in flight (4 loads).
        if (kt == NKT - 1) asm volatile("s_waitcnt vmcnt(0)" ::: "memory");
        else               asm volatile("s_waitcnt vmcnt(4)" ::: "memory");
        BARRIER_RAW();
        frag a[4], bq[4];
#pragma unroll
        for (int mi = 0; mi < 4; ++mi)
            a[mi] = *(const frag*)&AsB[p][sw_off(mi * 16 + fr, q)];
#pragma unroll
        for (int ni = 0; ni < 4; ++ni)
            bq[ni] = *(const frag*)&BsB[p][sw_off(wn + ni * 16 + fr, q)];
        if (kt + 1 < NKT) stageB(kt + 1, 1 - p);          // issue B first...
        if (kt + 2 < NKT) loadCorners(kt + 2, nxt);       // ...then corners
        if (kt + 1 < NKT) interpStore(kt + 1, 1 - p, cur); // waits corners(kt+1) only
#pragma unroll
        for (int mi = 0; mi < 4; ++mi)
#pragma unroll
            for (int ni = 0; ni < 4; ++ni)
                acc[mi][ni] = __builtin_amdgcn_mfma_f32_16x16x32_bf16(
                    a[mi], bq[ni], acc[mi][ni], 0, 0, 0);
        asm volatile("s_waitcnt lgkmcnt(0)" ::: "memory");
    };
    for (int kt = 0; kt < NKT; kt += 2) {
        body(kt, 0, &crA[0], &crB[0]);
        body(kt + 1, 1, &crB[0], &crA[0]);
    }

    // ---- epilogue: out[b][n][h*64+w]; C/D col=fr(n), row=q*4+r(m) ----
#pragma unroll
    for (int ni = 0; ni < 4; ++ni) {
        int n_g = wn + ni * 16 + fr;
        float* outn = out + (((size_t)b * COUT + n_g) << 12) + (h << 6);
#pragma unroll
        for (int mi = 0; mi < 4; ++mi) {
            int wl = mi * 16 + q * 4;
            *(float4*)&outn[wl] = make_float4(acc[mi][ni][0], acc[mi][ni][1],
                                              acc[mi][ni][2], acc[mi][ni][3]);
        }
    }
}

extern "C" void kernel_launch(void* const* d_in, const int* in_sizes, int n_in,
                              void* d_out, int out_size, void* d_ws, size_t ws_size,
                              hipStream_t stream) {
    const float* x  = (const float*)d_in[0];
    const float* ow = (const float*)d_in[1];
    const float* ob = (const float*)d_in[2];
    const float* mw = (const float*)d_in[3];
    const float* mb = (const float*)d_in[4];
    const float* rw = (const float*)d_in[5];
    float* out = (float*)d_out;
    char* ws = (char*)d_ws;

    u16*   xbf    = (u16*)(ws + WS_XBF);
    u16*   w2     = (u16*)(ws + WS_W2);
    u16*   w2om   = (u16*)(ws + WS_W2OM);
    float* offmod = (float*)(ws + WS_OFFMOD);

    k_nhwc2<<<dim3(HH, BB), 256, 0, stream>>>(x, xbf);
    k_pack_w2<<<(NKT * COUT * 32 + 255) / 256, 256, 0, stream>>>(rw, w2);
    k_pack_w2om<<<(NKT * 32 * 32 + 255) / 256, 256, 0, stream>>>(ow, mw, w2om);
    k_offmod4<<<dim3(HH, BB), 256, 0, stream>>>(xbf, w2om, ob, mb, offmod);
    k_deform4<<<dim3(HH, BB), 256, 0, stream>>>(xbf, offmod, w2, out);
}